// Round 3
// baseline (810.795 us; speedup 1.0000x reference)
//
#include <hip/hip_runtime.h>
#include <hip/hip_bf16.h>
#include <cmath>

// DXVAE: 7-node sequential graph GRU + VAE head, B=2048, H=1024. f32 I/O.
// R13 = R12 (789us: 64x128 tile, 4/CU, XCD swizzle, 2-phase prefetch) + ONE
// change: T4 counted-vmcnt 3-buffer pipeline. Per K-step:
//   s_waitcnt vmcnt(3)  <- tile t ready, tile t+1's loads STAY in flight
//   s_barrier (raw)     <- not __syncthreads (would re-insert vmcnt(0) drain)
//   issue tile t+2      <- buf[(t+2)%3] held tile t-1; all waves finished
//                          reading it before their step-t barrier -> safe
//   ds_read + 8 MFMA    <- compiler's own lgkmcnt protects reg deps
// Each tile gets ~2 compute-phases (~1200cy) of slack before its wait ->
// covers HBM-miss latency (~900cy); per-step stall ~0 (m218: counted vs
// drain0 was the entire T3 gain). Rule #18/#21 discipline: asm "memory"
// clobber + sched_barrier(0) after the barrier pin ds_reads AND the DMA
// issue below it. LDS 3x12KB=36.9KB -> still exactly 4 blocks/CU @ grid 1024.
// GRU fused into the GEMM epilogue via gate-interleaved W_aug (row=h*4+gate).

typedef __hip_bfloat16 bf16;
typedef __attribute__((ext_vector_type(8))) short bf16x8;   // 8 bf16 (4 VGPRs)
typedef __attribute__((ext_vector_type(4))) float f32x4;    // C/D frag

constexpr int BATCH = 2048;
constexpr int HD    = 1024;
constexpr int LDA   = 1056;          // augmented A stride (1024 h + 32 x-pad)
constexpr size_t BH = (size_t)BATCH * HD;

__device__ __forceinline__ bf16  f2bf(float v){ return __float2bfloat16(v); }
__device__ __forceinline__ float sigm(float x){ return 1.0f/(1.0f+__expf(-x)); }

__device__ __forceinline__ void async16(bf16* lds_wave_uniform, const bf16* g){
  __builtin_amdgcn_global_load_lds(
      (const __attribute__((address_space(1))) void*)g,
      (__attribute__((address_space(3))) void*)lds_wave_uniform, 16, 0, 0);
}
// 4 bf16 -> 4 f32 (exact: bits<<16)
__device__ __forceinline__ void ld4f(const bf16* p, float* o){
  ushort4 u = *reinterpret_cast<const ushort4*>(p);
  o[0] = __uint_as_float(((unsigned)u.x)<<16);
  o[1] = __uint_as_float(((unsigned)u.y)<<16);
  o[2] = __uint_as_float(((unsigned)u.z)<<16);
  o[3] = __uint_as_float(((unsigned)u.w)<<16);
}
__device__ __forceinline__ void st4bf(bf16* p, const float* v){
  bf16 o[4] = {f2bf(v[0]), f2bf(v[1]), f2bf(v[2]), f2bf(v[3])};
  *reinterpret_cast<ushort4*>(p) = *reinterpret_cast<const ushort4*>(o);
}

// ---------------------------------------------------------------------------
// Weight packing (once per launch)
// ---------------------------------------------------------------------------
// Gate-interleaved W_aug (4096 x 1056): row h*4+g.
// g0:[Whh_r|Wih_r] g1:[Whh_z|Wih_z] g2:[Whh_n|0] g3:[0|Wih_n]; x zero-padded.
__global__ __launch_bounds__(256) void pack_waug_i(
    const float* __restrict__ Whh, const float* __restrict__ Wih, int xw,
    bf16* __restrict__ out)
{
  int c = blockIdx.x;                 // 0..4095
  int h = c >> 2, g = c & 3;
  for (int ch = threadIdx.x; ch < 264; ch += 256){
    int f0 = ch*4;
    float v[4] = {0.f,0.f,0.f,0.f};
    if (f0 < 1024){
      if (g < 3){
        int src = (g==2) ? (2048+h) : (g*1024+h);
        const float4 t = *reinterpret_cast<const float4*>(Whh + (size_t)src*1024 + f0);
        v[0]=t.x; v[1]=t.y; v[2]=t.z; v[3]=t.w;
      }
    } else if (g != 2){
      int src = (g==0) ? h : (g==1) ? (1024+h) : (2048+h);
      int fx = f0 - 1024;
      #pragma unroll
      for (int j=0;j<4;++j) if (fx+j < xw) v[j] = Wih[(size_t)src*xw + fx + j];
    }
    st4bf(out + (size_t)c*LDA + f0, v);
  }
}

// Wgm (4096x1024) = [Wg[:,:1024]; Wg[:,1024:]; Wm[:,:1024]; Wm[:,1024:]]
__global__ __launch_bounds__(256) void pack_wgm(const float* __restrict__ Wg,
    const float* __restrict__ Wm, bf16* __restrict__ outW){
  int i = blockIdx.x*256 + threadIdx.x;          // < 4096*256
  int c = i >> 8, f0 = (i & 255)*4;
  int j = c >> 10, h = c & 1023;
  const float* src = (j < 2) ? Wg : Wm;
  float4 t = *reinterpret_cast<const float4*>(src + (size_t)h*2048 + ((j & 1) ? 1024 : 0) + f0);
  float v[4] = {t.x,t.y,t.z,t.w};
  st4bf(outW + (size_t)c*1024 + f0, v);
}

// Wms (512x1024) = [Wmu; Wstd]
__global__ __launch_bounds__(256) void pack_wms(const float* __restrict__ Wmu,
    const float* __restrict__ Wstd, bf16* __restrict__ outW){
  int i = blockIdx.x*256 + threadIdx.x;          // < 512*256
  int c = i >> 8, f0 = (i & 255)*4;
  const float* src = (c < 256) ? (Wmu + (size_t)c*1024) : (Wstd + (size_t)(c-256)*1024);
  float4 t = *reinterpret_cast<const float4*>(src + f0);
  float v[4] = {t.x,t.y,t.z,t.w};
  st4bf(outW + (size_t)c*1024 + f0, v);
}

// Xpad (7 x 2048 x 32): X[:,v,:27] zero-padded to 32, bf16
__global__ __launch_bounds__(256) void pack_xpad(const float* __restrict__ X,
    bf16* __restrict__ out){
  int i = blockIdx.x*256 + threadIdx.x;          // < 7*2048*32
  int f = i & 31, bv = i >> 5;
  int b = bv / 7, v = bv % 7;
  float val = (f < 27) ? X[((size_t)b*7 + v)*27 + f] : 0.f;
  out[((size_t)v*BATCH + b)*32 + f] = f2bf(val);
}
// XpadR (2048 x 32): X[:,0,:23] zero-padded, bf16
__global__ __launch_bounds__(256) void pack_xpr(const float* __restrict__ X,
    bf16* __restrict__ out){
  int i = blockIdx.x*256 + threadIdx.x;          // < 2048*32
  int f = i & 31, b = i >> 5;
  float val = (f < 23) ? X[(size_t)b*7*27 + f] : 0.f;
  out[(size_t)b*32 + f] = f2bf(val);
}

// ---------------------------------------------------------------------------
// Stage combine: Hin[b, 0:1024] = sum_{k>v} sigm(p*Pg1+s*Pg2+bg)*(p*Pm1+s*Pm2)
// Hin[b, 1024:1056] = x-tail. v==6: empty loop -> zeros + tail.
// ---------------------------------------------------------------------------
__global__ __launch_bounds__(256) void combine_k(
    const bf16* __restrict__ P, const int* __restrict__ adj,
    const float* __restrict__ bg, const bf16* __restrict__ tailsrc,
    bf16* __restrict__ Hin, int v)
{
  int t  = threadIdx.x;
  int b  = blockIdx.x*2 + (t>>7);
  int tl = t & 127;
  int h0 = tl*8;
  float acc[8] = {0,0,0,0,0,0,0,0};
  float bgv[8];
  { const float4 a = *reinterpret_cast<const float4*>(bg + h0);
    const float4 c = *reinterpret_cast<const float4*>(bg + h0 + 4);
    bgv[0]=a.x;bgv[1]=a.y;bgv[2]=a.z;bgv[3]=a.w;bgv[4]=c.x;bgv[5]=c.y;bgv[6]=c.z;bgv[7]=c.w; }
  for (int k=v+1;k<7;++k){
    bool p = adj[b*49 + k*7 + v] > 0;
    bool s = adj[b*49 + v*7 + k] > 0;
    if (!p && !s) continue;
    const bf16* base = P + (size_t)(k-1)*4*BH + (size_t)b*HD + h0;
    float g1[8], g2[8], m1[8], m2[8];
    ld4f(base,          g1); ld4f(base+4,        g1+4);
    ld4f(base+BH,       g2); ld4f(base+BH+4,     g2+4);
    ld4f(base+2*BH,     m1); ld4f(base+2*BH+4,   m1+4);
    ld4f(base+3*BH,     m2); ld4f(base+3*BH+4,   m2+4);
    #pragma unroll
    for (int u=0;u<8;++u){
      float gg = (p?g1[u]:0.f) + (s?g2[u]:0.f);
      float mm = (p?m1[u]:0.f) + (s?m2[u]:0.f);
      acc[u] += sigm(gg + bgv[u]) * mm;
    }
  }
  st4bf(Hin + (size_t)b*LDA + h0,     acc);
  st4bf(Hin + (size_t)b*LDA + h0 + 4, acc+4);
  if (tl < 4){   // x-tail: 32 elems per row, 4 threads x 8
    const ushort4* s0 = reinterpret_cast<const ushort4*>(tailsrc + (size_t)b*32 + tl*8);
    ushort4* d0 = reinterpret_cast<ushort4*>(Hin + (size_t)b*LDA + 1024 + tl*8);
    d0[0] = s0[0]; d0[1] = s0[1];
  }
}

// ---------------------------------------------------------------------------
// 64x128-tile GEMM, m97-style staging + counted-vmcnt 3-buffer pipeline.
// C = A(2048xK)@W^T. 4 waves, wave w owns N-cols [w*32, w*32+32):
// B wave-private (2 async16), A shared across waves (1 async16 each,
// staging 16 rows). BK=32. Steady-state K-step:
//   s_waitcnt vmcnt(3); s_barrier; issue tile t+2; ds_read+8 MFMA.
// Tile t's loads were issued 2 steps (~1200cy compute) before their wait ->
// even HBM-miss (~900cy) is covered; vmcnt never drains to 0 mid-loop.
// swz=1: flat grid 1024, bijective XCD swizzle (xcd=id&7 -> 16bx x 8by
// rectangle per XCD). swz=0: plain 2-D grid.
// MODE 0: gate-interleaved GRU (N=4096): epilogue h' via LDS gather.
// MODE 1: P-plane output (N=4096, plane-major rows)
// MODE 2: mu/std head (N=512, f32 out, bias+softplus)
// ---------------------------------------------------------------------------
template<int MODE>
__global__ __launch_bounds__(256) void gemm_t(
    const bf16* __restrict__ A, const bf16* __restrict__ Bw,
    bf16* __restrict__ out, float* __restrict__ outF,
    const float* __restrict__ bias1, const float* __restrict__ bias2,
    const int* __restrict__ adj, const bf16* __restrict__ xpad,
    int lda, int ldb, int kb, int ktot, int v, int tailw, int swz)
{
  // 18432 bf16 = 36.9 KB: three staging buffers of 6144 (As 64x32 @ +0,
  // Bs 4x(32x32) @ +2048). MODE-0 epilogue reuses [0, 8704).
  __shared__ __align__(16) bf16 S[18432];
  const int tid  = threadIdx.x;
  int bx, by;
  if (swz){ int xcd = blockIdx.x & 7, s = blockIdx.x >> 3;   // s in [0,128)
    bx = ((xcd & 1) << 4) | (s & 15);                        // [0,32)
    by = ((xcd >> 1) << 3) | (s >> 4);                       // [0,32)
  } else { bx = blockIdx.x; by = blockIdx.y; }
  const int rb0  = bx*64, n0 = by*128;
  const int lane = tid & 63, w = tid >> 6;
  const int quad = lane >> 4, l15 = lane & 15;
  const int sr   = lane >> 2, sc = (lane & 3)*8;   // staging lane -> row/col

  // staging sources (lane-resolved); dest base is wave-uniform (HW adds lane*16)
  const bf16* gA = A  + (size_t)(rb0 + w*16 + sr)*lda + sc;
  const bf16* gB = Bw + (size_t)(n0  + w*32 + sr)*ldb + sc;
  const int oA = w*512;          // wave w stages A rows [w*16, w*16+16)
  const int oB = 2048 + w*1024;  // wave w's private B tile (32x32)

  const int nt = (ktot - kb) >> 5;   // number of BK=32 K-steps (>=1)
  // prologue: issue tiles 0 and 1
  async16(S + oA,       gA + kb);
  async16(S + oB,       gB + kb);
  async16(S + oB + 512, gB + kb + (size_t)16*ldb);
  if (nt > 1){
    bf16* b1 = S + 6144;
    async16(b1 + oA,       gA + kb + 32);
    async16(b1 + oB,       gB + kb + 32);
    async16(b1 + oB + 512, gB + kb + 32 + (size_t)16*ldb);
  }

  f32x4 acc[4][2] = {};
  int bi = 0;                        // current buffer = t % 3
  for (int t = 0; t < nt; ++t){
    // wait for tile t (own 3 loads), keep tile t+1's in flight
    if (t + 1 < nt) asm volatile("s_waitcnt vmcnt(3)" ::: "memory");
    else            asm volatile("s_waitcnt vmcnt(0)" ::: "memory");
    __builtin_amdgcn_s_barrier();          // all waves have tile t staged
    __builtin_amdgcn_sched_barrier(0);     // pin: no hoist of ds_read/DMA
    if (t + 2 < nt){
      int bn = bi + 2; if (bn >= 3) bn -= 3;
      bf16* bp = S + bn*6144;              // held tile t-1: all waves done
      const int k2 = kb + (t+2)*32;        // reading it before this barrier
      async16(bp + oA,       gA + k2);
      async16(bp + oB,       gB + k2);
      async16(bp + oB + 512, gB + k2 + (size_t)16*ldb);
    }
    const bf16* As = S + bi*6144;
    const bf16* Bs = As + 2048;
    bf16x8 af0 = *reinterpret_cast<const bf16x8*>(&As[(  0 + l15)*32 + quad*8]);
    bf16x8 af1 = *reinterpret_cast<const bf16x8*>(&As[( 16 + l15)*32 + quad*8]);
    bf16x8 af2 = *reinterpret_cast<const bf16x8*>(&As[( 32 + l15)*32 + quad*8]);
    bf16x8 af3 = *reinterpret_cast<const bf16x8*>(&As[( 48 + l15)*32 + quad*8]);
    bf16x8 bf0 = *reinterpret_cast<const bf16x8*>(&Bs[w*1024 + (     l15)*32 + quad*8]);
    bf16x8 bf1 = *reinterpret_cast<const bf16x8*>(&Bs[w*1024 + (16 + l15)*32 + quad*8]);
    acc[0][0] = __builtin_amdgcn_mfma_f32_16x16x32_bf16(af0, bf0, acc[0][0], 0,0,0);
    acc[0][1] = __builtin_amdgcn_mfma_f32_16x16x32_bf16(af0, bf1, acc[0][1], 0,0,0);
    acc[1][0] = __builtin_amdgcn_mfma_f32_16x16x32_bf16(af1, bf0, acc[1][0], 0,0,0);
    acc[1][1] = __builtin_amdgcn_mfma_f32_16x16x32_bf16(af1, bf1, acc[1][1], 0,0,0);
    acc[2][0] = __builtin_amdgcn_mfma_f32_16x16x32_bf16(af2, bf0, acc[2][0], 0,0,0);
    acc[2][1] = __builtin_amdgcn_mfma_f32_16x16x32_bf16(af2, bf1, acc[2][1], 0,0,0);
    acc[3][0] = __builtin_amdgcn_mfma_f32_16x16x32_bf16(af3, bf0, acc[3][0], 0,0,0);
    acc[3][1] = __builtin_amdgcn_mfma_f32_16x16x32_bf16(af3, bf1, acc[3][1], 0,0,0);
    if (++bi == 3) bi = 0;
  }

  if (MODE == 1 || MODE == 2){
    #pragma unroll
    for (int tm=0;tm<4;++tm)
      #pragma unroll
      for (int tn=0;tn<2;++tn)
        #pragma unroll
        for (int i=0;i<4;++i){
          int b = rb0 + tm*16 + quad*4 + i;
          int c = n0  + w*32 + tn*16 + l15;
          float val = acc[tm][tn][i];
          if (MODE == 1){
            out[((size_t)(c>>10)*BATCH + b)*HD + (c & 1023)] = f2bf(val);
          } else {
            if (c < 256){
              outF[(size_t)b*256 + c] = val + bias1[c];
            } else {
              val += bias2[c-256];
              val = fmaxf(val,0.f) + log1pf(__expf(-fabsf(val)));   // softplus
              outF[(size_t)BATCH*256 + (size_t)b*256 + (c-256)] = val;
            }
          }
        }
    return;
  }

  // ---- MODE 0: GRU epilogue. Stage acc tile (64x128) to LDS, gather gates.
  __syncthreads();   // all waves done with final-tile ds_reads before S reuse
  #pragma unroll
  for (int tm=0;tm<4;++tm)
    #pragma unroll
    for (int tn=0;tn<2;++tn)
      #pragma unroll
      for (int i=0;i<4;++i){
        int r = tm*16 + quad*4 + i;
        int c = w*32 + tn*16 + l15;
        S[r*136 + c] = f2bf(acc[tm][tn][i]);
      }
  __syncthreads();
  {
    const int row = tid >> 2;                 // 0..63
    const int hs  = (tid & 3)*8;              // 0,8,16,24 (h within block's 32)
    const int b   = rb0 + row;
    const int hbase = by*32;
    bf16 hv[16];  // only 8 used; padded for uint4 stores
    #pragma unroll
    for (int j4=0; j4<8; j4+=4){
      const int hg = hbase + hs + j4;
      float4 bir = *reinterpret_cast<const float4*>(bias1 + hg);
      float4 biz = *reinterpret_cast<const float4*>(bias1 + 1024 + hg);
      float4 bin = *reinterpret_cast<const float4*>(bias1 + 2048 + hg);
      float4 bhr = *reinterpret_cast<const float4*>(bias2 + hg);
      float4 bhz = *reinterpret_cast<const float4*>(bias2 + 1024 + hg);
      float4 bhn = *reinterpret_cast<const float4*>(bias2 + 2048 + hg);
      const float* p_ir = &bir.x; const float* p_iz = &biz.x; const float* p_in = &bin.x;
      const float* p_hr = &bhr.x; const float* p_hz = &bhz.x; const float* p_hn = &bhn.x;
      float ho[4];
      ld4f(A + (size_t)b*lda + hg, ho);       // h_old = first 1024 cols of A
      #pragma unroll
      for (int jj=0; jj<4; ++jj){
        float g[4];
        ld4f(&S[row*136 + (hs + j4 + jj)*4], g);   // gates r,z,hn,inn
        float r = sigm(g[0] + p_ir[jj] + p_hr[jj]);
        float z = sigm(g[1] + p_iz[jj] + p_hz[jj]);
        float n = tanhf(g[3] + p_in[jj] + r*(g[2] + p_hn[jj]));
        hv[j4+jj] = f2bf((1.f - z)*n + z*ho[jj]);
      }
    }
    *reinterpret_cast<uint4*>(out + (size_t)b*lda + hbase + hs) =
        *reinterpret_cast<const uint4*>(&hv[0]);
  }
  // self-masked x-tail for the NEXT GEMM (GRU-l), written once (by==0)
  if (tailw && by == 0){
    const int b = rb0 + (tid>>2), f0 = (tid&3)*8;
    bool self = adj[b*49 + v*8] > 0;
    uint4 tv = {0u,0u,0u,0u};
    if (self) tv = *reinterpret_cast<const uint4*>(xpad + (size_t)b*32 + f0);
    *reinterpret_cast<uint4*>(out + (size_t)b*lda + 1024 + f0) = tv;
  }
}

// ---------------------------------------------------------------------------
extern "C" void kernel_launch(void* const* d_in, const int* in_sizes, int n_in,
                              void* d_out, int out_size, void* d_ws, size_t ws_size,
                              hipStream_t stream)
{
  const float* X    = (const float*)d_in[0];
  const int*   adj  = (const int*)  d_in[1];
  const float* Wihc = (const float*)d_in[2];
  const float* Whhc = (const float*)d_in[3];
  const float* bihc = (const float*)d_in[4];
  const float* bhhc = (const float*)d_in[5];
  const float* Wihl = (const float*)d_in[6];
  const float* Whhl = (const float*)d_in[7];
  const float* bihl = (const float*)d_in[8];
  const float* bhhl = (const float*)d_in[9];
  const float* Wihr = (const float*)d_in[10];
  const float* Whhr = (const float*)d_in[11];
  const float* bihr = (const float*)d_in[12];
  const float* bhhr = (const float*)d_in[13];
  const float* Wg   = (const float*)d_in[14];
  const float* bg   = (const float*)d_in[15];
  const float* Wm   = (const float*)d_in[16];
  const float* Wmu  = (const float*)d_in[17];
  const float* bmu  = (const float*)d_in[18];
  const float* Wstd = (const float*)d_in[19];
  const float* bstd = (const float*)d_in[20];
  float* out = (float*)d_out;

  // Workspace (bf16 elems, all 16B-aligned)
  bf16* P    = (bf16*)d_ws;                      // 24*BH (6 nodes x 4 planes)
  bf16* Hin  = P    + 24*BH;                     // 2048*1056
  bf16* Hva  = Hin  + (size_t)BATCH*LDA;
  bf16* Hvb  = Hva  + (size_t)BATCH*LDA;
  bf16* Wca  = Hvb  + (size_t)BATCH*LDA;         // 4096*1056 (gate-interleaved)
  bf16* Wla  = Wca  + (size_t)4096*LDA;
  bf16* Wra  = Wla  + (size_t)4096*LDA;
  bf16* Wgm  = Wra  + (size_t)4096*LDA;          // 4096*1024
  bf16* Wms  = Wgm  + (size_t)4096*1024;         // 512*1024
  bf16* Xp   = Wms  + (size_t)512*1024;          // 7*2048*32
  bf16* XpR  = Xp   + (size_t)7*BATCH*32;        // 2048*32

  pack_waug_i<<<4096, 256, 0, stream>>>(Whhc, Wihc, 27, Wca);
  pack_waug_i<<<4096, 256, 0, stream>>>(Whhl, Wihl, 27, Wla);
  pack_waug_i<<<4096, 256, 0, stream>>>(Whhr, Wihr, 23, Wra);
  pack_wgm  <<<4096, 256, 0, stream>>>(Wg, Wm, Wgm);
  pack_wms  <<<512,  256, 0, stream>>>(Wmu, Wstd, Wms);
  pack_xpad <<<1792, 256, 0, stream>>>(X, Xp);
  pack_xpr  <<<256,  256, 0, stream>>>(X, XpR);

  for (int v=6; v>=1; --v){
    const bf16* xt = Xp + (size_t)v*BATCH*32;
    combine_k<<<1024, 256, 0, stream>>>(P, adj, bg, xt, Hin, v);
    // GRU-c (v==6: h==0 -> only the x-tail K-step, kb=1024)
    gemm_t<0><<<1024, 256, 0, stream>>>(Hin, Wca, Hva, nullptr,
        bihc, bhhc, adj, xt, LDA, LDA, (v==6)?1024:0, 1056, v, 1, 1);
    // GRU-l (x tail in Hva was self-loop-masked by GRU-c's epilogue)
    gemm_t<0><<<1024, 256, 0, stream>>>(Hva, Wla, Hvb, nullptr,
        bihl, bhhl, adj, nullptr, LDA, LDA, 0, 1056, v, 0, 1);
    // P projections for node v
    gemm_t<1><<<1024, 256, 0, stream>>>(Hvb, Wgm, P + (size_t)(v-1)*4*BH,
        nullptr, nullptr, nullptr, nullptr, nullptr, LDA, 1024, 0, 1024, 0, 0, 1);
  }
  combine_k<<<1024, 256, 0, stream>>>(P, adj, bg, XpR, Hin, 0);
  gemm_t<0><<<1024, 256, 0, stream>>>(Hin, Wra, Hva, nullptr,
      bihr, bhhr, adj, nullptr, LDA, LDA, 0, 1056, 0, 0, 1);
  gemm_t<2><<<dim3(32,4), 256, 0, stream>>>(Hva, Wms, nullptr, out,
      bmu, bstd, nullptr, nullptr, LDA, 1024, 0, 1024, 0, 0, 0);
}

// Round 5
// 668.426 us; speedup vs baseline: 1.2130x; 1.2130x over previous
//
#include <hip/hip_runtime.h>
#include <hip/hip_bf16.h>
#include <cmath>

// DXVAE: 7-node sequential graph GRU + VAE head, B=2048, H=1024. f32 I/O.
// R15 = R14's geometry thesis with R14's suspected bug (workspace growth ->
// OOB on tail regions Wms/Xp/XpR; signature: std err 468 = uninit garbage,
// mu err 0.35 = bounded GRU error from garbage X) removed:
//   - LDA stays 1056 (workspace byte-identical to proven R12)
//   - 128x128 tile, BK=64 as TWO BK=32 subtiles, each with R12's exact
//     proven LDS layout (32-col rows), staging map and read formula.
//     NO XOR swizzle anywhere.
//   - 512 thr (8 waves 2x4), grid 512 = exactly 2 blocks/CU, 16 waves/CU
//     (same TLP as R12; fixes R11's occupancy failure).
//   - K=1056 = 16 full steps + 1 half step (subtile 0 only, uniform branch).
//   - R12's prefetch-then-one-__syncthreads dbuf loop (R13's counted-vmcnt
//     regressed). Barriers per GEMM: 33 -> 17. B-duplication bx 32 -> 16.
// GRU fused into the GEMM epilogue via gate-interleaved W_aug (row=h*4+gate).

typedef __hip_bfloat16 bf16;
typedef __attribute__((ext_vector_type(8))) short bf16x8;   // 8 bf16 (4 VGPRs)
typedef __attribute__((ext_vector_type(4))) float f32x4;    // C/D frag

constexpr int BATCH = 2048;
constexpr int HD    = 1024;
constexpr int LDA   = 1056;          // augmented A stride (1024 h + 32 x-pad)
constexpr size_t BH = (size_t)BATCH * HD;

__device__ __forceinline__ bf16  f2bf(float v){ return __float2bfloat16(v); }
__device__ __forceinline__ float sigm(float x){ return 1.0f/(1.0f+__expf(-x)); }

__device__ __forceinline__ void async16(bf16* lds_wave_uniform, const bf16* g){
  __builtin_amdgcn_global_load_lds(
      (const __attribute__((address_space(1))) void*)g,
      (__attribute__((address_space(3))) void*)lds_wave_uniform, 16, 0, 0);
}
// 4 bf16 -> 4 f32 (exact: bits<<16)
__device__ __forceinline__ void ld4f(const bf16* p, float* o){
  ushort4 u = *reinterpret_cast<const ushort4*>(p);
  o[0] = __uint_as_float(((unsigned)u.x)<<16);
  o[1] = __uint_as_float(((unsigned)u.y)<<16);
  o[2] = __uint_as_float(((unsigned)u.z)<<16);
  o[3] = __uint_as_float(((unsigned)u.w)<<16);
}
__device__ __forceinline__ void st4bf(bf16* p, const float* v){
  bf16 o[4] = {f2bf(v[0]), f2bf(v[1]), f2bf(v[2]), f2bf(v[3])};
  *reinterpret_cast<ushort4*>(p) = *reinterpret_cast<const ushort4*>(o);
}

// ---------------------------------------------------------------------------
// Weight packing (once per launch) — R12-exact
// ---------------------------------------------------------------------------
// Gate-interleaved W_aug (4096 x 1056): row h*4+g.
// g0:[Whh_r|Wih_r] g1:[Whh_z|Wih_z] g2:[Whh_n|0] g3:[0|Wih_n]; x zero-padded.
__global__ __launch_bounds__(256) void pack_waug_i(
    const float* __restrict__ Whh, const float* __restrict__ Wih, int xw,
    bf16* __restrict__ out)
{
  int c = blockIdx.x;                 // 0..4095
  int h = c >> 2, g = c & 3;
  for (int ch = threadIdx.x; ch < 264; ch += 256){
    int f0 = ch*4;
    float v[4] = {0.f,0.f,0.f,0.f};
    if (f0 < 1024){
      if (g < 3){
        int src = (g==2) ? (2048+h) : (g*1024+h);
        const float4 t = *reinterpret_cast<const float4*>(Whh + (size_t)src*1024 + f0);
        v[0]=t.x; v[1]=t.y; v[2]=t.z; v[3]=t.w;
      }
    } else if (g != 2){
      int src = (g==0) ? h : (g==1) ? (1024+h) : (2048+h);
      int fx = f0 - 1024;
      #pragma unroll
      for (int j=0;j<4;++j) if (fx+j < xw) v[j] = Wih[(size_t)src*xw + fx + j];
    }
    st4bf(out + (size_t)c*LDA + f0, v);
  }
}

// Wgm (4096x1024) = [Wg[:,:1024]; Wg[:,1024:]; Wm[:,:1024]; Wm[:,1024:]]
__global__ __launch_bounds__(256) void pack_wgm(const float* __restrict__ Wg,
    const float* __restrict__ Wm, bf16* __restrict__ outW){
  int i = blockIdx.x*256 + threadIdx.x;          // < 4096*256
  int c = i >> 8, f0 = (i & 255)*4;
  int j = c >> 10, h = c & 1023;
  const float* src = (j < 2) ? Wg : Wm;
  float4 t = *reinterpret_cast<const float4*>(src + (size_t)h*2048 + ((j & 1) ? 1024 : 0) + f0);
  float v[4] = {t.x,t.y,t.z,t.w};
  st4bf(outW + (size_t)c*1024 + f0, v);
}

// Wms (512x1024) = [Wmu; Wstd]
__global__ __launch_bounds__(256) void pack_wms(const float* __restrict__ Wmu,
    const float* __restrict__ Wstd, bf16* __restrict__ outW){
  int i = blockIdx.x*256 + threadIdx.x;          // < 512*256
  int c = i >> 8, f0 = (i & 255)*4;
  const float* src = (c < 256) ? (Wmu + (size_t)c*1024) : (Wstd + (size_t)(c-256)*1024);
  float4 t = *reinterpret_cast<const float4*>(src + f0);
  float v[4] = {t.x,t.y,t.z,t.w};
  st4bf(outW + (size_t)c*1024 + f0, v);
}

// Xpad (7 x 2048 x 32): X[:,v,:27] zero-padded to 32, bf16
__global__ __launch_bounds__(256) void pack_xpad(const float* __restrict__ X,
    bf16* __restrict__ out){
  int i = blockIdx.x*256 + threadIdx.x;          // < 7*2048*32
  int f = i & 31, bv = i >> 5;
  int b = bv / 7, v = bv % 7;
  float val = (f < 27) ? X[((size_t)b*7 + v)*27 + f] : 0.f;
  out[((size_t)v*BATCH + b)*32 + f] = f2bf(val);
}
// XpadR (2048 x 32): X[:,0,:23] zero-padded, bf16
__global__ __launch_bounds__(256) void pack_xpr(const float* __restrict__ X,
    bf16* __restrict__ out){
  int i = blockIdx.x*256 + threadIdx.x;          // < 2048*32
  int f = i & 31, b = i >> 5;
  float val = (f < 23) ? X[(size_t)b*7*27 + f] : 0.f;
  out[(size_t)b*32 + f] = f2bf(val);
}

// ---------------------------------------------------------------------------
// Stage combine: Hin[b, 0:1024] = sum_{k>v} sigm(p*Pg1+s*Pg2+bg)*(p*Pm1+s*Pm2)
// Hin[b, 1024:1056] = x-tail. v==6: empty loop -> zeros + tail. (R12-exact)
// ---------------------------------------------------------------------------
__global__ __launch_bounds__(256) void combine_k(
    const bf16* __restrict__ P, const int* __restrict__ adj,
    const float* __restrict__ bg, const bf16* __restrict__ tailsrc,
    bf16* __restrict__ Hin, int v)
{
  int t  = threadIdx.x;
  int b  = blockIdx.x*2 + (t>>7);
  int tl = t & 127;
  int h0 = tl*8;
  float acc[8] = {0,0,0,0,0,0,0,0};
  float bgv[8];
  { const float4 a = *reinterpret_cast<const float4*>(bg + h0);
    const float4 c = *reinterpret_cast<const float4*>(bg + h0 + 4);
    bgv[0]=a.x;bgv[1]=a.y;bgv[2]=a.z;bgv[3]=a.w;bgv[4]=c.x;bgv[5]=c.y;bgv[6]=c.z;bgv[7]=c.w; }
  for (int k=v+1;k<7;++k){
    bool p = adj[b*49 + k*7 + v] > 0;
    bool s = adj[b*49 + v*7 + k] > 0;
    if (!p && !s) continue;
    const bf16* base = P + (size_t)(k-1)*4*BH + (size_t)b*HD + h0;
    float g1[8], g2[8], m1[8], m2[8];
    ld4f(base,          g1); ld4f(base+4,        g1+4);
    ld4f(base+BH,       g2); ld4f(base+BH+4,     g2+4);
    ld4f(base+2*BH,     m1); ld4f(base+2*BH+4,   m1+4);
    ld4f(base+3*BH,     m2); ld4f(base+3*BH+4,   m2+4);
    #pragma unroll
    for (int u=0;u<8;++u){
      float gg = (p?g1[u]:0.f) + (s?g2[u]:0.f);
      float mm = (p?m1[u]:0.f) + (s?m2[u]:0.f);
      acc[u] += sigm(gg + bgv[u]) * mm;
    }
  }
  st4bf(Hin + (size_t)b*LDA + h0,     acc);
  st4bf(Hin + (size_t)b*LDA + h0 + 4, acc+4);
  if (tl < 4){   // x-tail: 32 elems per row, 4 threads x 8
    const ushort4* s0 = reinterpret_cast<const ushort4*>(tailsrc + (size_t)b*32 + tl*8);
    ushort4* d0 = reinterpret_cast<ushort4*>(Hin + (size_t)b*LDA + 1024 + tl*8);
    d0[0] = s0[0]; d0[1] = s0[1];
  }
}

// ---------------------------------------------------------------------------
// 128x128-tile GEMM, BK=64 as two BK=32 subtiles with R12's exact LDS layout
// (32-col rows; staging sr=lane>>2, sc=(lane&3)*8; no swizzle). 8 waves 2x4,
// wave = 64x32 output sub-tile, acc[4][2]. R12 prefetch dbuf loop: stage t+1
// before computing t, ONE __syncthreads per step. K=1056 -> 16 full + 1 half
// step (subtile 0 only); MODE 1/2 K=1024 -> 16 full.
// Per block-step: 64 MFMA (full), 24 KB staged, 1 barrier.
// swz=1: flat grid 512, bijective XCD swizzle (xcd=id&7 -> 8bx x 8by
// rectangle per XCD: A 2.2MB + B 2.2MB ~ one 4MB L2). swz=0: plain 2-D grid.
// MODE 0: gate-interleaved GRU (N=4096): epilogue h' via LDS gather.
// MODE 1: P-plane output (N=4096, plane-major rows)
// MODE 2: mu/std head (N=512, f32 out, bias+softplus)
// ---------------------------------------------------------------------------
template<int MODE>
__global__ __launch_bounds__(512, 4) void gemm_t(
    const bf16* __restrict__ A, const bf16* __restrict__ Bw,
    bf16* __restrict__ out, float* __restrict__ outF,
    const float* __restrict__ bias1, const float* __restrict__ bias2,
    const int* __restrict__ adj, const bf16* __restrict__ xpad,
    int lda, int ldb, int kb, int ktot, int v, int tailw, int swz)
{
  // 32768 bf16 = 64 KB: 2 buffers x 16384. Buffer layout: As0(128x32)@0,
  // Bs0@4096, As1@8192, Bs1@12288. MODE-0 epilogue reuses [0,17400).
  __shared__ __align__(16) bf16 S[32768];
  const int tid  = threadIdx.x;
  int bx, by;
  if (swz){ int xcd = blockIdx.x & 7, s = blockIdx.x >> 3;   // s in [0,64)
    bx = ((xcd & 1) << 3) | (s & 7);                         // [0,16)
    by = ((xcd >> 1) << 3) | (s >> 3);                       // [0,32)
  } else { bx = blockIdx.x; by = blockIdx.y; }
  const int rb0  = bx*128, n0 = by*128;
  const int lane = tid & 63, w = tid >> 6;
  const int quad = lane >> 4, l15 = lane & 15;
  const int sr   = lane >> 2, sc = (lane & 3)*8;   // staging lane -> row/col
  const int wr   = w >> 2,    wc = w & 3;          // wave -> 64x32 sub-tile

  // staging sources (lane-resolved); dest base is wave-uniform (HW adds lane*16)
  const bf16* gA = A  + (size_t)(rb0 + w*16 + sr)*lda + sc;
  const bf16* gB = Bw + (size_t)(n0  + w*16 + sr)*ldb + sc;
  const int dA = w*512;           // wave w stages A rows [w*16, w*16+16)
  const int dB = 4096 + w*512;    // wave w stages B rows [w*16, w*16+16)

  const int nt = (ktot - kb + 63) >> 6;   // 64-wide steps; last may be half

  // prologue: stage tile 0 into buffer 0
  {
    async16(S + dA, gA + kb);
    async16(S + dB, gB + kb);
    if (ktot - kb > 32){
      async16(S + 8192 + dA, gA + kb + 32);
      async16(S + 8192 + dB, gB + kb + 32);
    }
  }
  __syncthreads();

  f32x4 acc[4][2] = {};
  for (int t = 0; t < nt; ++t){
    const int k0 = kb + t*64;
    if (t + 1 < nt){                 // issue NEXT tile before computing current
      bf16* bp = S + ((t+1)&1)*16384;
      const int k1 = k0 + 64;
      async16(bp + dA, gA + k1);
      async16(bp + dB, gB + k1);
      if (ktot - k1 > 32){
        async16(bp + 8192 + dA, gA + k1 + 32);
        async16(bp + 8192 + dB, gB + k1 + 32);
      }
    }
    const bf16* buf = S + (t&1)*16384;
    {   // subtile 0 (k0..k0+32) — R12's exact read formula
      const bf16* As = buf;
      const bf16* Bs = buf + 4096;
      bf16x8 aa[4], bb[2];
      #pragma unroll
      for (int m=0;m<4;++m)
        aa[m] = *reinterpret_cast<const bf16x8*>(&As[(wr*64 + m*16 + l15)*32 + quad*8]);
      #pragma unroll
      for (int n=0;n<2;++n)
        bb[n] = *reinterpret_cast<const bf16x8*>(&Bs[(wc*32 + n*16 + l15)*32 + quad*8]);
      #pragma unroll
      for (int m=0;m<4;++m)
        #pragma unroll
        for (int n=0;n<2;++n)
          acc[m][n] = __builtin_amdgcn_mfma_f32_16x16x32_bf16(aa[m], bb[n], acc[m][n], 0,0,0);
    }
    if (ktot - k0 > 32){   // subtile 1 (k0+32..k0+64); uniform branch
      const bf16* As = buf + 8192;
      const bf16* Bs = buf + 12288;
      bf16x8 aa[4], bb[2];
      #pragma unroll
      for (int m=0;m<4;++m)
        aa[m] = *reinterpret_cast<const bf16x8*>(&As[(wr*64 + m*16 + l15)*32 + quad*8]);
      #pragma unroll
      for (int n=0;n<2;++n)
        bb[n] = *reinterpret_cast<const bf16x8*>(&Bs[(wc*32 + n*16 + l15)*32 + quad*8]);
      #pragma unroll
      for (int m=0;m<4;++m)
        #pragma unroll
        for (int n=0;n<2;++n)
          acc[m][n] = __builtin_amdgcn_mfma_f32_16x16x32_bf16(aa[m], bb[n], acc[m][n], 0,0,0);
    }
    __syncthreads();                 // drains vmcnt(0): next buffer ready;
  }                                  // also protects buffer we just read

  if (MODE == 1 || MODE == 2){
    #pragma unroll
    for (int tm=0;tm<4;++tm)
      #pragma unroll
      for (int tn=0;tn<2;++tn)
        #pragma unroll
        for (int i=0;i<4;++i){
          int b = rb0 + wr*64 + tm*16 + quad*4 + i;
          int c = n0  + wc*32 + tn*16 + l15;
          float val = acc[tm][tn][i];
          if (MODE == 1){
            out[((size_t)(c>>10)*BATCH + b)*HD + (c & 1023)] = f2bf(val);
          } else {
            if (c < 256){
              outF[(size_t)b*256 + c] = val + bias1[c];
            } else {
              val += bias2[c-256];
              val = fmaxf(val,0.f) + log1pf(__expf(-fabsf(val)));   // softplus
              outF[(size_t)BATCH*256 + (size_t)b*256 + (c-256)] = val;
            }
          }
        }
    return;
  }

  // ---- MODE 0: GRU epilogue. Stage acc tile (128x128) to LDS, gather gates.
  #pragma unroll
  for (int tm=0;tm<4;++tm)
    #pragma unroll
    for (int tn=0;tn<2;++tn)
      #pragma unroll
      for (int i=0;i<4;++i){
        int r = wr*64 + tm*16 + quad*4 + i;
        int c = wc*32 + tn*16 + l15;
        S[r*136 + c] = f2bf(acc[tm][tn][i]);
      }
  __syncthreads();
  {
    const int row = tid >> 2;                 // 0..127
    const int hs  = (tid & 3)*8;              // 0,8,16,24 (h within block's 32)
    const int b   = rb0 + row;
    const int hbase = by*32;
    bf16 hv[16];  // only 8 used; padded for uint4 stores
    #pragma unroll
    for (int j4=0; j4<8; j4+=4){
      const int hg = hbase + hs + j4;
      float4 bir = *reinterpret_cast<const float4*>(bias1 + hg);
      float4 biz = *reinterpret_cast<const float4*>(bias1 + 1024 + hg);
      float4 bin = *reinterpret_cast<const float4*>(bias1 + 2048 + hg);
      float4 bhr = *reinterpret_cast<const float4*>(bias2 + hg);
      float4 bhz = *reinterpret_cast<const float4*>(bias2 + 1024 + hg);
      float4 bhn = *reinterpret_cast<const float4*>(bias2 + 2048 + hg);
      const float* p_ir = &bir.x; const float* p_iz = &biz.x; const float* p_in = &bin.x;
      const float* p_hr = &bhr.x; const float* p_hz = &bhz.x; const float* p_hn = &bhn.x;
      float ho[4];
      ld4f(A + (size_t)b*lda + hg, ho);       // h_old = first 1024 cols of A
      #pragma unroll
      for (int jj=0; jj<4; ++jj){
        float g[4];
        ld4f(&S[row*136 + (hs + j4 + jj)*4], g);   // gates r,z,hn,inn
        float r = sigm(g[0] + p_ir[jj] + p_hr[jj]);
        float z = sigm(g[1] + p_iz[jj] + p_hz[jj]);
        float n = tanhf(g[3] + p_in[jj] + r*(g[2] + p_hn[jj]));
        hv[j4+jj] = f2bf((1.f - z)*n + z*ho[jj]);
      }
    }
    *reinterpret_cast<uint4*>(out + (size_t)b*lda + hbase + hs) =
        *reinterpret_cast<const uint4*>(&hv[0]);
  }
  // self-masked x-tail for the NEXT GEMM (GRU-l), written once (by==0)
  if (tailw && by == 0){
    const int b2 = rb0 + (tid>>2), f0 = (tid&3)*8;   // 128 rows x 4 x 8 cols
    bool self = adj[b2*49 + v*8] > 0;
    uint4 tv = {0u,0u,0u,0u};
    if (self) tv = *reinterpret_cast<const uint4*>(xpad + (size_t)b2*32 + f0);
    *reinterpret_cast<uint4*>(out + (size_t)b2*lda + 1024 + f0) = tv;
  }
}

// ---------------------------------------------------------------------------
extern "C" void kernel_launch(void* const* d_in, const int* in_sizes, int n_in,
                              void* d_out, int out_size, void* d_ws, size_t ws_size,
                              hipStream_t stream)
{
  const float* X    = (const float*)d_in[0];
  const int*   adj  = (const int*)  d_in[1];
  const float* Wihc = (const float*)d_in[2];
  const float* Whhc = (const float*)d_in[3];
  const float* bihc = (const float*)d_in[4];
  const float* bhhc = (const float*)d_in[5];
  const float* Wihl = (const float*)d_in[6];
  const float* Whhl = (const float*)d_in[7];
  const float* bihl = (const float*)d_in[8];
  const float* bhhl = (const float*)d_in[9];
  const float* Wihr = (const float*)d_in[10];
  const float* Whhr = (const float*)d_in[11];
  const float* bihr = (const float*)d_in[12];
  const float* bhhr = (const float*)d_in[13];
  const float* Wg   = (const float*)d_in[14];
  const float* bg   = (const float*)d_in[15];
  const float* Wm   = (const float*)d_in[16];
  const float* Wmu  = (const float*)d_in[17];
  const float* bmu  = (const float*)d_in[18];
  const float* Wstd = (const float*)d_in[19];
  const float* bstd = (const float*)d_in[20];
  float* out = (float*)d_out;

  // Workspace (bf16 elems, all 16B-aligned) — byte-identical to R12's layout
  bf16* P    = (bf16*)d_ws;                      // 24*BH (6 nodes x 4 planes)
  bf16* Hin  = P    + 24*BH;                     // 2048*1056
  bf16* Hva  = Hin  + (size_t)BATCH*LDA;
  bf16* Hvb  = Hva  + (size_t)BATCH*LDA;
  bf16* Wca  = Hvb  + (size_t)BATCH*LDA;         // 4096*1056 (gate-interleaved)
  bf16* Wla  = Wca  + (size_t)4096*LDA;
  bf16* Wra  = Wla  + (size_t)4096*LDA;
  bf16* Wgm  = Wra  + (size_t)4096*LDA;          // 4096*1024
  bf16* Wms  = Wgm  + (size_t)4096*1024;         // 512*1024
  bf16* Xp   = Wms  + (size_t)512*1024;          // 7*2048*32
  bf16* XpR  = Xp   + (size_t)7*BATCH*32;        // 2048*32

  pack_waug_i<<<4096, 256, 0, stream>>>(Whhc, Wihc, 27, Wca);
  pack_waug_i<<<4096, 256, 0, stream>>>(Whhl, Wihl, 27, Wla);
  pack_waug_i<<<4096, 256, 0, stream>>>(Whhr, Wihr, 23, Wra);
  pack_wgm  <<<4096, 256, 0, stream>>>(Wg, Wm, Wgm);
  pack_wms  <<<512,  256, 0, stream>>>(Wmu, Wstd, Wms);
  pack_xpad <<<1792, 256, 0, stream>>>(X, Xp);
  pack_xpr  <<<256,  256, 0, stream>>>(X, XpR);

  for (int v=6; v>=1; --v){
    const bf16* xt = Xp + (size_t)v*BATCH*32;
    combine_k<<<1024, 256, 0, stream>>>(P, adj, bg, xt, Hin, v);
    // GRU-c (v==6: h==0 -> only the x-tail half-step, kb=1024)
    gemm_t<0><<<512, 512, 0, stream>>>(Hin, Wca, Hva, nullptr,
        bihc, bhhc, adj, xt, LDA, LDA, (v==6)?1024:0, 1056, v, 1, 1);
    // GRU-l (x tail in Hva was self-loop-masked by GRU-c's epilogue)
    gemm_t<0><<<512, 512, 0, stream>>>(Hva, Wla, Hvb, nullptr,
        bihl, bhhl, adj, nullptr, LDA, LDA, 0, 1056, v, 0, 1);
    // P projections for node v
    gemm_t<1><<<512, 512, 0, stream>>>(Hvb, Wgm, P + (size_t)(v-1)*4*BH,
        nullptr, nullptr, nullptr, nullptr, nullptr, LDA, 1024, 0, 1024, 0, 0, 1);
  }
  combine_k<<<1024, 256, 0, stream>>>(P, adj, bg, XpR, Hin, 0);
  gemm_t<0><<<512, 512, 0, stream>>>(Hin, Wra, Hva, nullptr,
      bihr, bhhr, adj, nullptr, LDA, LDA, 0, 1056, 0, 0, 1);
  gemm_t<2><<<dim3(16,4), 512, 0, stream>>>(Hva, Wms, nullptr, out,
      bmu, bstd, nullptr, nullptr, LDA, 1024, 0, 1024, 0, 0, 0);
}